// Round 7
// baseline (890.626 us; speedup 1.0000x reference)
//
#include <hip/hip_runtime.h>
#include <hip/hip_bf16.h>

#define NUM_USERS 100000
#define NUM_ITEMS 50000
#define EMBED     64
#define S_NNZ     (NUM_USERS * 32)
#define R_NNZ     (NUM_USERS * 50)
#define BATCH     8192
#define NPASS     8

// ---------------- CSR build (S only) ----------------

__global__ void k_hist(const int* __restrict__ rows, int* __restrict__ cnt, int nnz) {
    int e = blockIdx.x * blockDim.x + threadIdx.x;
    if (e < nnz) atomicAdd(&cnt[rows[e]], 1);
}

__global__ __launch_bounds__(1024) void k_scan1(const int* __restrict__ cnt, int* __restrict__ excl,
                                                int* __restrict__ bsums, int n) {
    __shared__ int buf[1024];
    int t = threadIdx.x;
    int i = blockIdx.x * 1024 + t;
    int x = (i < n) ? cnt[i] : 0;
    buf[t] = x;
    __syncthreads();
    for (int off = 1; off < 1024; off <<= 1) {
        int y = (t >= off) ? buf[t - off] : 0;
        __syncthreads();
        buf[t] += y;
        __syncthreads();
    }
    if (i < n) excl[i] = buf[t] - x;
    if (t == 1023) bsums[blockIdx.x] = buf[1023];
}

__global__ __launch_bounds__(1024) void k_scan2(int* __restrict__ bsums, int nb, int* __restrict__ total_slot) {
    __shared__ int buf[1024];
    int t = threadIdx.x;
    int x = (t < nb) ? bsums[t] : 0;
    buf[t] = x;
    __syncthreads();
    for (int off = 1; off < 1024; off <<= 1) {
        int y = (t >= off) ? buf[t - off] : 0;
        __syncthreads();
        buf[t] += y;
        __syncthreads();
    }
    if (t < nb) bsums[t] = buf[t] - x;
    if (t == 1023) total_slot[0] = buf[1023];
}

__global__ void k_scan3(int* __restrict__ rowptr, int* __restrict__ wofs, const int* __restrict__ bsums, int n) {
    int i = blockIdx.x * blockDim.x + threadIdx.x;
    if (i < n) {
        int v = rowptr[i] + bsums[i >> 10];
        rowptr[i] = v;
        wofs[i]   = v;
    }
}

// partitioned counting-sort scatter: pass handles rows in [lo,hi) so the
// destination window (~3.2 MB) stays L2-resident -> full-line writebacks.
__global__ void k_scatter_pass(const int* __restrict__ rows, const int* __restrict__ cols,
                               const float* __restrict__ vals, int* __restrict__ wofs,
                               int2* __restrict__ colval, int nnz, int lo, int hi) {
    int e = blockIdx.x * blockDim.x + threadIdx.x;
    if (e >= nnz) return;
    int r = rows[e];
    if (r < lo || r >= hi) return;
    int pos = atomicAdd(&wofs[r], 1);
    colval[pos] = make_int2(cols[e], __float_as_int(vals[e]));
}

// ---------------- SpMM (CSR gather, packed edges, predicated 8-wide) ----------------
__global__ __launch_bounds__(256) void k_spmm_csr(const int* __restrict__ rowptr,
                                                  const int2* __restrict__ colval,
                                                  const float* __restrict__ X,
                                                  float* __restrict__ Y, int n_rows) {
    int w    = blockIdx.x * (blockDim.x >> 6) + (threadIdx.x >> 6);
    int lane = threadIdx.x & 63;
    if (w >= n_rows) return;
    int beg = rowptr[w], end = rowptr[w + 1];
    float acc = 0.0f;
    for (int j = beg; j < end; j += 8) {
        int2 cv[8];
#pragma unroll
        for (int u = 0; u < 8; ++u) {
            int jj = j + u;
            cv[u] = (jj < end) ? colval[jj] : make_int2(0, 0);
        }
        float x[8];
#pragma unroll
        for (int u = 0; u < 8; ++u) x[u] = X[(size_t)cv[u].x * EMBED + lane];
#pragma unroll
        for (int u = 0; u < 8; ++u) acc = fmaf(__int_as_float(cv[u].y), x[u], acc);
    }
    Y[(size_t)w * EMBED + lane] = acc;
}

// Batch-restricted SpMM: wave i computes (S @ X)[bu[i]] -> Agg2[i]
__global__ __launch_bounds__(256) void k_spmm_batch(const int* __restrict__ rowptr,
                                                    const int2* __restrict__ colval,
                                                    const float* __restrict__ X,
                                                    const int* __restrict__ bu,
                                                    float* __restrict__ Agg2, int n) {
    int w    = blockIdx.x * (blockDim.x >> 6) + (threadIdx.x >> 6);
    int lane = threadIdx.x & 63;
    if (w >= n) return;
    int r   = bu[w];
    int beg = rowptr[r], end = rowptr[r + 1];
    float acc = 0.0f;
    for (int j = beg; j < end; j += 8) {
        int2 cv[8];
#pragma unroll
        for (int u = 0; u < 8; ++u) {
            int jj = j + u;
            cv[u] = (jj < end) ? colval[jj] : make_int2(0, 0);
        }
        float x[8];
#pragma unroll
        for (int u = 0; u < 8; ++u) x[u] = X[(size_t)cv[u].x * EMBED + lane];
#pragma unroll
        for (int u = 0; u < 8; ++u) acc = fmaf(__int_as_float(cv[u].y), x[u], acc);
    }
    Agg2[(size_t)w * EMBED + lane] = acc;
}

// ---------------- dense layers ----------------
__global__ __launch_bounds__(256) void k_layer(const float* __restrict__ Agg,
                                               const float* __restrict__ Uin,
                                               float* __restrict__ Uout,
                                               const float* __restrict__ W,
                                               const float* __restrict__ b) {
    __shared__ float Wl[128 * 64];
    __shared__ float xs[16][128];
    int t = threadIdx.x;
    for (int i = t; i < 128 * 64; i += 256) Wl[i] = W[i];
    int rl = t >> 6;
    int c  = t & 63;
    int rbase = blockIdx.x * 16;
#pragma unroll
    for (int q = 0; q < 4; ++q) {
        int rr = rbase + rl * 4 + q;
        if (rr < NUM_USERS) {
            xs[rl * 4 + q][c]      = Agg[(size_t)rr * EMBED + c];
            xs[rl * 4 + q][64 + c] = Uin[(size_t)rr * EMBED + c];
        }
    }
    __syncthreads();
    float bias = b[c];
#pragma unroll
    for (int q = 0; q < 4; ++q) {
        int rr = rbase + rl * 4 + q;
        if (rr >= NUM_USERS) break;
        float acc = bias;
#pragma unroll
        for (int k = 0; k < 128; ++k) acc = fmaf(xs[rl * 4 + q][k], Wl[k * 64 + c], acc);
        Uout[(size_t)rr * EMBED + c] = fmaxf(acc, 0.0f);
    }
}

__global__ __launch_bounds__(256) void k_layer_batch(const float* __restrict__ Agg2,
                                                     const float* __restrict__ Uin,
                                                     const int* __restrict__ bu,
                                                     float* __restrict__ out0,
                                                     const float* __restrict__ W,
                                                     const float* __restrict__ b) {
    __shared__ float Wl[128 * 64];
    __shared__ float xs[16][128];
    int t = threadIdx.x;
    for (int i = t; i < 128 * 64; i += 256) Wl[i] = W[i];
    int rl = t >> 6;
    int c  = t & 63;
    int rbase = blockIdx.x * 16;
#pragma unroll
    for (int q = 0; q < 4; ++q) {
        int s = rbase + rl * 4 + q;
        if (s < BATCH) {
            xs[rl * 4 + q][c]      = Agg2[(size_t)s * EMBED + c];
            xs[rl * 4 + q][64 + c] = Uin[(size_t)bu[s] * EMBED + c];
        }
    }
    __syncthreads();
    float bias = b[c];
#pragma unroll
    for (int q = 0; q < 4; ++q) {
        int s = rbase + rl * 4 + q;
        if (s >= BATCH) break;
        float acc = bias;
#pragma unroll
        for (int k = 0; k < 128; ++k) acc = fmaf(xs[rl * 4 + q][k], Wl[k * 64 + c], acc);
        out0[(size_t)s * EMBED + c] = fmaxf(acc, 0.0f);
    }
}

// ---------------- R handling (no CSR): chain map + edge filter ----------------

__global__ void k_chain(const int* __restrict__ bu, int* __restrict__ head,
                        int* __restrict__ nxt, int n) {
    int i = blockIdx.x * blockDim.x + threadIdx.x;
    if (i < n) nxt[i] = atomicExch(&head[bu[i]], i);
}

__global__ __launch_bounds__(256) void k_filter(const int* __restrict__ rows,
                                                const int* __restrict__ cols,
                                                const float* __restrict__ vals,
                                                const int* __restrict__ head,
                                                const int* __restrict__ nxt,
                                                const float* __restrict__ V,
                                                float* __restrict__ out0, int nnz) {
    int e    = blockIdx.x * blockDim.x + threadIdx.x;
    int lane = threadIdx.x & 63;
    int r = (e < nnz) ? rows[e] : -1;
    int h = (r >= 0) ? head[r] : -1;
    unsigned long long mask = __ballot(h >= 0);
    int   c = 0;
    float v = 0.0f;
    if (h >= 0) { c = cols[e]; v = vals[e]; }
    while (mask) {
        int l = __ffsll((long long)mask) - 1;
        mask &= mask - 1;
        int   cc = __shfl(c, l);
        float vv = __shfl(v, l);
        int   hh = __shfl(h, l);
        float x  = vv * V[(size_t)cc * EMBED + lane];
        while (hh >= 0) {
            atomicAdd(&out0[(size_t)hh * EMBED + lane], x);
            hh = nxt[hh];
        }
    }
}

// ---------------- final gathers (bp/bn only) ----------------
__global__ void k_gather2(const float* __restrict__ V,
                          const int* __restrict__ bp, const int* __restrict__ bn,
                          float* __restrict__ out) {
    int i = blockIdx.x * blockDim.x + threadIdx.x;
    if (i >= BATCH * EMBED) return;
    int row = i >> 6, l = i & 63;
    out[BATCH * EMBED + i]     = V[(size_t)bp[row] * EMBED + l];
    out[2 * BATCH * EMBED + i] = V[(size_t)bn[row] * EMBED + l];
}

// ---------------- launch ----------------

extern "C" void kernel_launch(void* const* d_in, const int* in_sizes, int n_in,
                              void* d_out, int out_size, void* d_ws, size_t ws_size,
                              hipStream_t stream) {
    const int*   batch_user = (const int*)d_in[0];
    const int*   batch_pos  = (const int*)d_in[1];
    const int*   batch_neg  = (const int*)d_in[2];
    const float* U     = (const float*)d_in[3];
    const float* V     = (const float*)d_in[4];
    const float* W0    = (const float*)d_in[5];
    const float* b0    = (const float*)d_in[6];
    const float* W1    = (const float*)d_in[7];
    const float* b1    = (const float*)d_in[8];
    const int*   S_row = (const int*)d_in[9];
    const int*   S_col = (const int*)d_in[10];
    const float* S_val = (const float*)d_in[11];
    const int*   R_row = (const int*)d_in[12];
    const int*   R_col = (const int*)d_in[13];
    const float* R_val = (const float*)d_in[14];
    float* out = (float*)d_out;

    const size_t tabElems = (size_t)NUM_USERS * EMBED;   // 6.4M floats

    // workspace layout (byte offsets)
    char* wsb = (char*)d_ws;
    size_t o = 0;
    float* A       = (float*)(wsb + o); o += tabElems * 4;            // U1
    float* B       = (float*)(wsb + o); o += tabElems * 4;            // agg
    float* Agg2    = (float*)(wsb + o); o += (size_t)BATCH * EMBED * 4;
    int*   rowptrS = (int*)(wsb + o);   o += (NUM_USERS + 1) * 4;
    int*   wofs    = (int*)(wsb + o);   o += NUM_USERS * 4;
    int*   bsums   = (int*)(wsb + o);   o += 1024 * 4;
    int*   head    = (int*)(wsb + o);   o += NUM_USERS * 4;
    int*   nxt     = (int*)(wsb + o);   o += BATCH * 4;
    o = (o + 7) & ~(size_t)7;
    int2*  colvalS = (int2*)(wsb + o);  o += (size_t)S_NNZ * 8;

    const int nb = (NUM_USERS + 1023) / 1024;
    const int spmm_blocks  = (NUM_USERS * 64 + 255) / 256;
    const int layer_blocks = (NUM_USERS + 15) / 16;

    // ---- CSR of S ----
    hipMemsetAsync(wofs, 0, NUM_USERS * sizeof(int), stream);
    k_hist<<<(S_NNZ + 255) / 256, 256, 0, stream>>>(S_row, wofs, S_NNZ);
    k_scan1<<<nb, 1024, 0, stream>>>(wofs, rowptrS, bsums, NUM_USERS);
    k_scan2<<<1, 1024, 0, stream>>>(bsums, nb, &rowptrS[NUM_USERS]);
    k_scan3<<<(NUM_USERS + 255) / 256, 256, 0, stream>>>(rowptrS, wofs, bsums, NUM_USERS);
    {   // partitioned scatter: destination window per pass ~3.2 MB (L2-resident)
        const int rpp = (NUM_USERS + NPASS - 1) / NPASS;   // 12500 rows/pass
        for (int p = 0; p < NPASS; ++p) {
            int lo = p * rpp;
            int hi = (lo + rpp < NUM_USERS) ? lo + rpp : NUM_USERS;
            k_scatter_pass<<<(S_NNZ + 255) / 256, 256, 0, stream>>>(
                S_row, S_col, S_val, wofs, colvalS, S_NNZ, lo, hi);
        }
    }

    // ---- layer 0 (full) ----
    k_spmm_csr<<<spmm_blocks, 256, 0, stream>>>(rowptrS, colvalS, U, B, NUM_USERS);
    k_layer<<<layer_blocks, 256, 0, stream>>>(B, U, A, W0, b0);

    // ---- chain map for R (user -> batch slots) ----
    hipMemsetAsync(head, 0xFF, NUM_USERS * sizeof(int), stream);
    k_chain<<<(BATCH + 255) / 256, 256, 0, stream>>>(batch_user, head, nxt, BATCH);

    // ---- layer 1 (batch-restricted), writes u2 into out0 ----
    k_spmm_batch<<<(BATCH * 64 + 255) / 256, 256, 0, stream>>>(rowptrS, colvalS, A, batch_user, Agg2, BATCH);
    k_layer_batch<<<(BATCH + 15) / 16, 256, 0, stream>>>(Agg2, A, batch_user, out, W1, b1);

    // ---- out0 += (R @ V)[batch rows] ----
    k_filter<<<(R_NNZ + 255) / 256, 256, 0, stream>>>(R_row, R_col, R_val, head, nxt, V, out, R_NNZ);

    // ---- bp/bn gathers ----
    k_gather2<<<(BATCH * EMBED + 255) / 256, 256, 0, stream>>>(V, batch_pos, batch_neg, out);
}

// Round 8
// 791.914 us; speedup vs baseline: 1.1246x; 1.1246x over previous
//
#include <hip/hip_runtime.h>
#include <hip/hip_bf16.h>

#define NUM_USERS 100000
#define NUM_ITEMS 50000
#define EMBED     64
#define S_NNZ     (NUM_USERS * 32)
#define R_NNZ     (NUM_USERS * 50)
#define BATCH     8192
#define NSHARD    8
#define ROWS_PER_SHARD ((NUM_USERS + NSHARD - 1) / NSHARD)   // 12500

// ---------------- CSR build (S only) ----------------

__global__ void k_hist(const int* __restrict__ rows, int* __restrict__ cnt, int nnz) {
    int e = blockIdx.x * blockDim.x + threadIdx.x;
    if (e < nnz) atomicAdd(&cnt[rows[e]], 1);
}

__global__ __launch_bounds__(1024) void k_scan1(const int* __restrict__ cnt, int* __restrict__ excl,
                                                int* __restrict__ bsums, int n) {
    __shared__ int buf[1024];
    int t = threadIdx.x;
    int i = blockIdx.x * 1024 + t;
    int x = (i < n) ? cnt[i] : 0;
    buf[t] = x;
    __syncthreads();
    for (int off = 1; off < 1024; off <<= 1) {
        int y = (t >= off) ? buf[t - off] : 0;
        __syncthreads();
        buf[t] += y;
        __syncthreads();
    }
    if (i < n) excl[i] = buf[t] - x;
    if (t == 1023) bsums[blockIdx.x] = buf[1023];
}

__global__ __launch_bounds__(1024) void k_scan2(int* __restrict__ bsums, int nb, int* __restrict__ total_slot) {
    __shared__ int buf[1024];
    int t = threadIdx.x;
    int x = (t < nb) ? bsums[t] : 0;
    buf[t] = x;
    __syncthreads();
    for (int off = 1; off < 1024; off <<= 1) {
        int y = (t >= off) ? buf[t - off] : 0;
        __syncthreads();
        buf[t] += y;
        __syncthreads();
    }
    if (t < nb) bsums[t] = buf[t] - x;
    if (t == 1023) total_slot[0] = buf[1023];
}

__global__ void k_scan3(int* __restrict__ rowptr, int* __restrict__ wofs, const int* __restrict__ bsums, int n) {
    int i = blockIdx.x * blockDim.x + threadIdx.x;
    if (i < n) {
        int v = rowptr[i] + bsums[i >> 10];
        rowptr[i] = v;
        wofs[i]   = v;
    }
}

// XCD-sharded counting-sort scatter (single launch).
// shard = blockIdx & 7 -> with round-robin block->XCD dispatch, each XCD
// commits only rows in its 12500-row range, so its random writes stay inside
// a ~3.2 MB window that fits the per-XCD 4 MB L2 (full-line writebacks).
// The 8x re-read of the edge stream is concurrent -> shared L3 serves 7/8.
__global__ void k_scatter_shard(const int* __restrict__ rows, const int* __restrict__ cols,
                                const float* __restrict__ vals, int* __restrict__ wofs,
                                int2* __restrict__ colval, int nnz) {
    int shard = blockIdx.x & (NSHARD - 1);
    int e     = (blockIdx.x >> 3) * blockDim.x + threadIdx.x;
    if (e >= nnz) return;
    int r  = rows[e];
    int lo = shard * ROWS_PER_SHARD;
    if (r < lo || r >= lo + ROWS_PER_SHARD) return;
    int pos = atomicAdd(&wofs[r], 1);
    colval[pos] = make_int2(cols[e], __float_as_int(vals[e]));
}

// ---------------- SpMM (CSR gather, packed edges, unroll x8) ----------------
__global__ __launch_bounds__(256) void k_spmm_csr(const int* __restrict__ rowptr,
                                                  const int2* __restrict__ colval,
                                                  const float* __restrict__ X,
                                                  float* __restrict__ Y, int n_rows) {
    int w    = blockIdx.x * (blockDim.x >> 6) + (threadIdx.x >> 6);
    int lane = threadIdx.x & 63;
    if (w >= n_rows) return;
    int beg = rowptr[w], end = rowptr[w + 1];
    float acc = 0.0f;
    int j    = beg;
    int jend = beg + ((end - beg) & ~7);
    for (; j < jend; j += 8) {
        int2 cv[8];
#pragma unroll
        for (int u = 0; u < 8; ++u) cv[u] = colval[j + u];
        float x[8];
#pragma unroll
        for (int u = 0; u < 8; ++u) x[u] = X[(size_t)cv[u].x * EMBED + lane];
#pragma unroll
        for (int u = 0; u < 8; ++u) acc = fmaf(__int_as_float(cv[u].y), x[u], acc);
    }
    for (; j < end; ++j) acc = fmaf(__int_as_float(colval[j].y), X[(size_t)colval[j].x * EMBED + lane], acc);
    Y[(size_t)w * EMBED + lane] = acc;
}

// Batch-restricted SpMM: wave i computes (S @ X)[bu[i]] -> Agg2[i]
__global__ __launch_bounds__(256) void k_spmm_batch(const int* __restrict__ rowptr,
                                                    const int2* __restrict__ colval,
                                                    const float* __restrict__ X,
                                                    const int* __restrict__ bu,
                                                    float* __restrict__ Agg2, int n) {
    int w    = blockIdx.x * (blockDim.x >> 6) + (threadIdx.x >> 6);
    int lane = threadIdx.x & 63;
    if (w >= n) return;
    int r   = bu[w];
    int beg = rowptr[r], end = rowptr[r + 1];
    float acc = 0.0f;
    int j    = beg;
    int jend = beg + ((end - beg) & ~7);
    for (; j < jend; j += 8) {
        int2 cv[8];
#pragma unroll
        for (int u = 0; u < 8; ++u) cv[u] = colval[j + u];
        float x[8];
#pragma unroll
        for (int u = 0; u < 8; ++u) x[u] = X[(size_t)cv[u].x * EMBED + lane];
#pragma unroll
        for (int u = 0; u < 8; ++u) acc = fmaf(__int_as_float(cv[u].y), x[u], acc);
    }
    for (; j < end; ++j) acc = fmaf(__int_as_float(colval[j].y), X[(size_t)colval[j].x * EMBED + lane], acc);
    Agg2[(size_t)w * EMBED + lane] = acc;
}

// ---------------- dense layers ----------------
__global__ __launch_bounds__(256) void k_layer(const float* __restrict__ Agg,
                                               const float* __restrict__ Uin,
                                               float* __restrict__ Uout,
                                               const float* __restrict__ W,
                                               const float* __restrict__ b) {
    __shared__ float Wl[128 * 64];
    __shared__ float xs[16][128];
    int t = threadIdx.x;
    for (int i = t; i < 128 * 64; i += 256) Wl[i] = W[i];
    int rl = t >> 6;
    int c  = t & 63;
    int rbase = blockIdx.x * 16;
#pragma unroll
    for (int q = 0; q < 4; ++q) {
        int rr = rbase + rl * 4 + q;
        if (rr < NUM_USERS) {
            xs[rl * 4 + q][c]      = Agg[(size_t)rr * EMBED + c];
            xs[rl * 4 + q][64 + c] = Uin[(size_t)rr * EMBED + c];
        }
    }
    __syncthreads();
    float bias = b[c];
#pragma unroll
    for (int q = 0; q < 4; ++q) {
        int rr = rbase + rl * 4 + q;
        if (rr >= NUM_USERS) break;
        float acc = bias;
#pragma unroll
        for (int k = 0; k < 128; ++k) acc = fmaf(xs[rl * 4 + q][k], Wl[k * 64 + c], acc);
        Uout[(size_t)rr * EMBED + c] = fmaxf(acc, 0.0f);
    }
}

__global__ __launch_bounds__(256) void k_layer_batch(const float* __restrict__ Agg2,
                                                     const float* __restrict__ Uin,
                                                     const int* __restrict__ bu,
                                                     float* __restrict__ out0,
                                                     const float* __restrict__ W,
                                                     const float* __restrict__ b) {
    __shared__ float Wl[128 * 64];
    __shared__ float xs[16][128];
    int t = threadIdx.x;
    for (int i = t; i < 128 * 64; i += 256) Wl[i] = W[i];
    int rl = t >> 6;
    int c  = t & 63;
    int rbase = blockIdx.x * 16;
#pragma unroll
    for (int q = 0; q < 4; ++q) {
        int s = rbase + rl * 4 + q;
        if (s < BATCH) {
            xs[rl * 4 + q][c]      = Agg2[(size_t)s * EMBED + c];
            xs[rl * 4 + q][64 + c] = Uin[(size_t)bu[s] * EMBED + c];
        }
    }
    __syncthreads();
    float bias = b[c];
#pragma unroll
    for (int q = 0; q < 4; ++q) {
        int s = rbase + rl * 4 + q;
        if (s >= BATCH) break;
        float acc = bias;
#pragma unroll
        for (int k = 0; k < 128; ++k) acc = fmaf(xs[rl * 4 + q][k], Wl[k * 64 + c], acc);
        out0[(size_t)s * EMBED + c] = fmaxf(acc, 0.0f);
    }
}

// ---------------- R handling (no CSR): chain map + edge filter ----------------

__global__ void k_chain(const int* __restrict__ bu, int* __restrict__ head,
                        int* __restrict__ nxt, int n) {
    int i = blockIdx.x * blockDim.x + threadIdx.x;
    if (i < n) nxt[i] = atomicExch(&head[bu[i]], i);
}

__global__ __launch_bounds__(256) void k_filter(const int* __restrict__ rows,
                                                const int* __restrict__ cols,
                                                const float* __restrict__ vals,
                                                const int* __restrict__ head,
                                                const int* __restrict__ nxt,
                                                const float* __restrict__ V,
                                                float* __restrict__ out0, int nnz) {
    int e    = blockIdx.x * blockDim.x + threadIdx.x;
    int lane = threadIdx.x & 63;
    int r = (e < nnz) ? rows[e] : -1;
    int h = (r >= 0) ? head[r] : -1;
    unsigned long long mask = __ballot(h >= 0);
    int   c = 0;
    float v = 0.0f;
    if (h >= 0) { c = cols[e]; v = vals[e]; }
    while (mask) {
        int l = __ffsll((long long)mask) - 1;
        mask &= mask - 1;
        int   cc = __shfl(c, l);
        float vv = __shfl(v, l);
        int   hh = __shfl(h, l);
        float x  = vv * V[(size_t)cc * EMBED + lane];
        while (hh >= 0) {
            atomicAdd(&out0[(size_t)hh * EMBED + lane], x);
            hh = nxt[hh];
        }
    }
}

// ---------------- final gathers (bp/bn only) ----------------
__global__ void k_gather2(const float* __restrict__ V,
                          const int* __restrict__ bp, const int* __restrict__ bn,
                          float* __restrict__ out) {
    int i = blockIdx.x * blockDim.x + threadIdx.x;
    if (i >= BATCH * EMBED) return;
    int row = i >> 6, l = i & 63;
    out[BATCH * EMBED + i]     = V[(size_t)bp[row] * EMBED + l];
    out[2 * BATCH * EMBED + i] = V[(size_t)bn[row] * EMBED + l];
}

// ---------------- launch ----------------

extern "C" void kernel_launch(void* const* d_in, const int* in_sizes, int n_in,
                              void* d_out, int out_size, void* d_ws, size_t ws_size,
                              hipStream_t stream) {
    const int*   batch_user = (const int*)d_in[0];
    const int*   batch_pos  = (const int*)d_in[1];
    const int*   batch_neg  = (const int*)d_in[2];
    const float* U     = (const float*)d_in[3];
    const float* V     = (const float*)d_in[4];
    const float* W0    = (const float*)d_in[5];
    const float* b0    = (const float*)d_in[6];
    const float* W1    = (const float*)d_in[7];
    const float* b1    = (const float*)d_in[8];
    const int*   S_row = (const int*)d_in[9];
    const int*   S_col = (const int*)d_in[10];
    const float* S_val = (const float*)d_in[11];
    const int*   R_row = (const int*)d_in[12];
    const int*   R_col = (const int*)d_in[13];
    const float* R_val = (const float*)d_in[14];
    float* out = (float*)d_out;

    const size_t tabElems = (size_t)NUM_USERS * EMBED;   // 6.4M floats

    // workspace layout (byte offsets)
    char* wsb = (char*)d_ws;
    size_t o = 0;
    float* A       = (float*)(wsb + o); o += tabElems * 4;            // U1
    float* B       = (float*)(wsb + o); o += tabElems * 4;            // agg
    float* Agg2    = (float*)(wsb + o); o += (size_t)BATCH * EMBED * 4;
    int*   rowptrS = (int*)(wsb + o);   o += (NUM_USERS + 1) * 4;
    int*   wofs    = (int*)(wsb + o);   o += NUM_USERS * 4;
    int*   bsums   = (int*)(wsb + o);   o += 1024 * 4;
    int*   head    = (int*)(wsb + o);   o += NUM_USERS * 4;
    int*   nxt     = (int*)(wsb + o);   o += BATCH * 4;
    o = (o + 7) & ~(size_t)7;
    int2*  colvalS = (int2*)(wsb + o);  o += (size_t)S_NNZ * 8;

    const int nb = (NUM_USERS + 1023) / 1024;
    const int spmm_blocks  = (NUM_USERS * 64 + 255) / 256;
    const int layer_blocks = (NUM_USERS + 15) / 16;

    // ---- CSR of S ----
    hipMemsetAsync(wofs, 0, NUM_USERS * sizeof(int), stream);
    k_hist<<<(S_NNZ + 255) / 256, 256, 0, stream>>>(S_row, wofs, S_NNZ);
    k_scan1<<<nb, 1024, 0, stream>>>(wofs, rowptrS, bsums, NUM_USERS);
    k_scan2<<<1, 1024, 0, stream>>>(bsums, nb, &rowptrS[NUM_USERS]);
    k_scan3<<<(NUM_USERS + 255) / 256, 256, 0, stream>>>(rowptrS, wofs, bsums, NUM_USERS);
    {   // XCD-sharded scatter: one launch, 8x grid; block commits only its shard's rows
        const int nchunks = (S_NNZ + 255) / 256;
        k_scatter_shard<<<nchunks * NSHARD, 256, 0, stream>>>(S_row, S_col, S_val, wofs, colvalS, S_NNZ);
    }

    // ---- layer 0 (full) ----
    k_spmm_csr<<<spmm_blocks, 256, 0, stream>>>(rowptrS, colvalS, U, B, NUM_USERS);
    k_layer<<<layer_blocks, 256, 0, stream>>>(B, U, A, W0, b0);

    // ---- chain map for R (user -> batch slots) ----
    hipMemsetAsync(head, 0xFF, NUM_USERS * sizeof(int), stream);
    k_chain<<<(BATCH + 255) / 256, 256, 0, stream>>>(batch_user, head, nxt, BATCH);

    // ---- layer 1 (batch-restricted), writes u2 into out0 ----
    k_spmm_batch<<<(BATCH * 64 + 255) / 256, 256, 0, stream>>>(rowptrS, colvalS, A, batch_user, Agg2, BATCH);
    k_layer_batch<<<(BATCH + 15) / 16, 256, 0, stream>>>(Agg2, A, batch_user, out, W1, b1);

    // ---- out0 += (R @ V)[batch rows] ----
    k_filter<<<(R_NNZ + 255) / 256, 256, 0, stream>>>(R_row, R_col, R_val, head, nxt, V, out, R_NNZ);

    // ---- bp/bn gathers ----
    k_gather2<<<(BATCH * EMBED + 255) / 256, 256, 0, stream>>>(V, batch_pos, batch_neg, out);
}

// Round 9
// 622.168 us; speedup vs baseline: 1.4315x; 1.2728x over previous
//
#include <hip/hip_runtime.h>
#include <hip/hip_bf16.h>

#define NUM_USERS 100000
#define NUM_ITEMS 50000
#define EMBED     64
#define S_NNZ     (NUM_USERS * 32)
#define R_NNZ     (NUM_USERS * 50)
#define BATCH     8192

// bucket sort parameters: 256 buckets x 391 rows, 256 chunks x 12500 edges
#define NB    256
#define NCH   256
#define CHUNK (S_NNZ / NCH)      // 12500 (exact: 256*12500 = 3.2M)
#define BROWS 391                // 391*256 = 100096 >= NUM_USERS

// ---------------- two-pass bucket CSR build ----------------

// pass 1a: per-chunk bucket histogram -> cnt_t[bucket*NCH + chunk]
__global__ __launch_bounds__(256) void k_p1hist(const int* __restrict__ rows, int* __restrict__ cnt_t) {
    __shared__ int h[NB];
    int t = threadIdx.x, b = blockIdx.x;
    h[t] = 0;
    __syncthreads();
    int base = b * CHUNK;
    for (int i = t; i < CHUNK; i += 256) atomicAdd(&h[rows[base + i] / BROWS], 1);
    __syncthreads();
    cnt_t[t * NCH + b] = h[t];
}

// flat exclusive scan over 65536 ints (3 kernels, reused pattern)
__global__ __launch_bounds__(1024) void k_scan1(const int* __restrict__ cnt, int* __restrict__ excl,
                                                int* __restrict__ bsums, int n) {
    __shared__ int buf[1024];
    int t = threadIdx.x;
    int i = blockIdx.x * 1024 + t;
    int x = (i < n) ? cnt[i] : 0;
    buf[t] = x;
    __syncthreads();
    for (int off = 1; off < 1024; off <<= 1) {
        int y = (t >= off) ? buf[t - off] : 0;
        __syncthreads();
        buf[t] += y;
        __syncthreads();
    }
    if (i < n) excl[i] = buf[t] - x;
    if (t == 1023) bsums[blockIdx.x] = buf[1023];
}

__global__ __launch_bounds__(1024) void k_scan2(int* __restrict__ bsums, int nb, int* __restrict__ total_slot) {
    __shared__ int buf[1024];
    int t = threadIdx.x;
    int x = (t < nb) ? bsums[t] : 0;
    buf[t] = x;
    __syncthreads();
    for (int off = 1; off < 1024; off <<= 1) {
        int y = (t >= off) ? buf[t - off] : 0;
        __syncthreads();
        buf[t] += y;
        __syncthreads();
    }
    if (t < nb) bsums[t] = buf[t] - x;
    if (t == 1023) total_slot[0] = buf[1023];
}

__global__ void k_scan3b(int* __restrict__ a, const int* __restrict__ bsums, int n) {
    int i = blockIdx.x * blockDim.x + threadIdx.x;
    if (i < n) a[i] += bsums[i >> 10];
}

// pass 1b: write each chunk's edges into per-(chunk,bucket) contiguous runs
__global__ __launch_bounds__(256) void k_p1scatter(const int* __restrict__ rows, const int* __restrict__ cols,
                                                   const float* __restrict__ vals, const int* __restrict__ cnt_t,
                                                   int* __restrict__ tmpRow, int2* __restrict__ tmpCV) {
    __shared__ int cur[NB];
    int t = threadIdx.x, b = blockIdx.x;
    cur[t] = cnt_t[t * NCH + b];
    __syncthreads();
    int base = b * CHUNK;
    for (int i = t; i < CHUNK; i += 256) {
        int e = base + i;
        int r = rows[e];
        int pos = atomicAdd(&cur[r / BROWS], 1);
        tmpRow[pos] = r;
        tmpCV[pos]  = make_int2(cols[e], __float_as_int(vals[e]));
    }
}

// pass 2: exact CSR within each bucket (100 KB window, one block) + rowptr
__global__ __launch_bounds__(512) void k_p2(const int* __restrict__ tmpRow, const int2* __restrict__ tmpCV,
                                            const int* __restrict__ cnt_t,
                                            int* __restrict__ rowptr, int2* __restrict__ colval) {
    __shared__ int h[512];
    __shared__ int s[512];
    __shared__ int cur[BROWS + 1];
    int t = threadIdx.x, k = blockIdx.x;
    int beg = cnt_t[k * NCH];
    int end = (k < NB - 1) ? cnt_t[(k + 1) * NCH] : S_NNZ;
    h[t] = 0;
    __syncthreads();
    int rbase = k * BROWS;
    for (int j = beg + t; j < end; j += 512) atomicAdd(&h[tmpRow[j] - rbase], 1);
    __syncthreads();
    s[t] = h[t];
    __syncthreads();
    for (int off = 1; off < 512; off <<= 1) {
        int y = (t >= off) ? s[t - off] : 0;
        __syncthreads();
        s[t] += y;
        __syncthreads();
    }
    int excl = s[t] - h[t];
    int gr   = rbase + t;
    if (t <= BROWS && gr <= NUM_USERS) rowptr[gr] = beg + excl;
    if (t <= BROWS) cur[t] = beg + excl;
    __syncthreads();
    for (int j = beg + t; j < end; j += 512) {
        int pos = atomicAdd(&cur[tmpRow[j] - rbase], 1);
        colval[pos] = tmpCV[j];
    }
}

// ---------------- SpMM (CSR gather, packed edges, unroll x8) ----------------
__global__ __launch_bounds__(256) void k_spmm_csr(const int* __restrict__ rowptr,
                                                  const int2* __restrict__ colval,
                                                  const float* __restrict__ X,
                                                  float* __restrict__ Y, int n_rows) {
    int w    = blockIdx.x * (blockDim.x >> 6) + (threadIdx.x >> 6);
    int lane = threadIdx.x & 63;
    if (w >= n_rows) return;
    int beg = rowptr[w], end = rowptr[w + 1];
    float acc = 0.0f;
    int j    = beg;
    int jend = beg + ((end - beg) & ~7);
    for (; j < jend; j += 8) {
        int2 cv[8];
#pragma unroll
        for (int u = 0; u < 8; ++u) cv[u] = colval[j + u];
        float x[8];
#pragma unroll
        for (int u = 0; u < 8; ++u) x[u] = X[(size_t)cv[u].x * EMBED + lane];
#pragma unroll
        for (int u = 0; u < 8; ++u) acc = fmaf(__int_as_float(cv[u].y), x[u], acc);
    }
    for (; j < end; ++j) acc = fmaf(__int_as_float(colval[j].y), X[(size_t)colval[j].x * EMBED + lane], acc);
    Y[(size_t)w * EMBED + lane] = acc;
}

__global__ __launch_bounds__(256) void k_spmm_batch(const int* __restrict__ rowptr,
                                                    const int2* __restrict__ colval,
                                                    const float* __restrict__ X,
                                                    const int* __restrict__ bu,
                                                    float* __restrict__ Agg2, int n) {
    int w    = blockIdx.x * (blockDim.x >> 6) + (threadIdx.x >> 6);
    int lane = threadIdx.x & 63;
    if (w >= n) return;
    int r   = bu[w];
    int beg = rowptr[r], end = rowptr[r + 1];
    float acc = 0.0f;
    int j    = beg;
    int jend = beg + ((end - beg) & ~7);
    for (; j < jend; j += 8) {
        int2 cv[8];
#pragma unroll
        for (int u = 0; u < 8; ++u) cv[u] = colval[j + u];
        float x[8];
#pragma unroll
        for (int u = 0; u < 8; ++u) x[u] = X[(size_t)cv[u].x * EMBED + lane];
#pragma unroll
        for (int u = 0; u < 8; ++u) acc = fmaf(__int_as_float(cv[u].y), x[u], acc);
    }
    for (; j < end; ++j) acc = fmaf(__int_as_float(colval[j].y), X[(size_t)colval[j].x * EMBED + lane], acc);
    Agg2[(size_t)w * EMBED + lane] = acc;
}

// ---------------- dense layers ----------------
__global__ __launch_bounds__(256) void k_layer(const float* __restrict__ Agg,
                                               const float* __restrict__ Uin,
                                               float* __restrict__ Uout,
                                               const float* __restrict__ W,
                                               const float* __restrict__ b) {
    __shared__ float Wl[128 * 64];
    __shared__ float xs[16][128];
    int t = threadIdx.x;
    for (int i = t; i < 128 * 64; i += 256) Wl[i] = W[i];
    int rl = t >> 6;
    int c  = t & 63;
    int rbase = blockIdx.x * 16;
#pragma unroll
    for (int q = 0; q < 4; ++q) {
        int rr = rbase + rl * 4 + q;
        if (rr < NUM_USERS) {
            xs[rl * 4 + q][c]      = Agg[(size_t)rr * EMBED + c];
            xs[rl * 4 + q][64 + c] = Uin[(size_t)rr * EMBED + c];
        }
    }
    __syncthreads();
    float bias = b[c];
#pragma unroll
    for (int q = 0; q < 4; ++q) {
        int rr = rbase + rl * 4 + q;
        if (rr >= NUM_USERS) break;
        float acc = bias;
#pragma unroll
        for (int k = 0; k < 128; ++k) acc = fmaf(xs[rl * 4 + q][k], Wl[k * 64 + c], acc);
        Uout[(size_t)rr * EMBED + c] = fmaxf(acc, 0.0f);
    }
}

__global__ __launch_bounds__(256) void k_layer_batch(const float* __restrict__ Agg2,
                                                     const float* __restrict__ Uin,
                                                     const int* __restrict__ bu,
                                                     float* __restrict__ out0,
                                                     const float* __restrict__ W,
                                                     const float* __restrict__ b) {
    __shared__ float Wl[128 * 64];
    __shared__ float xs[16][128];
    int t = threadIdx.x;
    for (int i = t; i < 128 * 64; i += 256) Wl[i] = W[i];
    int rl = t >> 6;
    int c  = t & 63;
    int rbase = blockIdx.x * 16;
#pragma unroll
    for (int q = 0; q < 4; ++q) {
        int s = rbase + rl * 4 + q;
        if (s < BATCH) {
            xs[rl * 4 + q][c]      = Agg2[(size_t)s * EMBED + c];
            xs[rl * 4 + q][64 + c] = Uin[(size_t)bu[s] * EMBED + c];
        }
    }
    __syncthreads();
    float bias = b[c];
#pragma unroll
    for (int q = 0; q < 4; ++q) {
        int s = rbase + rl * 4 + q;
        if (s >= BATCH) break;
        float acc = bias;
#pragma unroll
        for (int k = 0; k < 128; ++k) acc = fmaf(xs[rl * 4 + q][k], Wl[k * 64 + c], acc);
        out0[(size_t)s * EMBED + c] = fmaxf(acc, 0.0f);
    }
}

// ---------------- R handling (no CSR): chain map + edge filter ----------------

__global__ void k_chain(const int* __restrict__ bu, int* __restrict__ head,
                        int* __restrict__ nxt, int n) {
    int i = blockIdx.x * blockDim.x + threadIdx.x;
    if (i < n) nxt[i] = atomicExch(&head[bu[i]], i);
}

__global__ __launch_bounds__(256) void k_filter(const int* __restrict__ rows,
                                                const int* __restrict__ cols,
                                                const float* __restrict__ vals,
                                                const int* __restrict__ head,
                                                const int* __restrict__ nxt,
                                                const float* __restrict__ V,
                                                float* __restrict__ out0, int nnz) {
    int e    = blockIdx.x * blockDim.x + threadIdx.x;
    int lane = threadIdx.x & 63;
    int r = (e < nnz) ? rows[e] : -1;
    int h = (r >= 0) ? head[r] : -1;
    unsigned long long mask = __ballot(h >= 0);
    int   c = 0;
    float v = 0.0f;
    if (h >= 0) { c = cols[e]; v = vals[e]; }
    while (mask) {
        int l = __ffsll((long long)mask) - 1;
        mask &= mask - 1;
        int   cc = __shfl(c, l);
        float vv = __shfl(v, l);
        int   hh = __shfl(h, l);
        float x  = vv * V[(size_t)cc * EMBED + lane];
        while (hh >= 0) {
            atomicAdd(&out0[(size_t)hh * EMBED + lane], x);
            hh = nxt[hh];
        }
    }
}

// ---------------- final gathers (bp/bn only) ----------------
__global__ void k_gather2(const float* __restrict__ V,
                          const int* __restrict__ bp, const int* __restrict__ bn,
                          float* __restrict__ out) {
    int i = blockIdx.x * blockDim.x + threadIdx.x;
    if (i >= BATCH * EMBED) return;
    int row = i >> 6, l = i & 63;
    out[BATCH * EMBED + i]     = V[(size_t)bp[row] * EMBED + l];
    out[2 * BATCH * EMBED + i] = V[(size_t)bn[row] * EMBED + l];
}

// ---------------- launch ----------------

extern "C" void kernel_launch(void* const* d_in, const int* in_sizes, int n_in,
                              void* d_out, int out_size, void* d_ws, size_t ws_size,
                              hipStream_t stream) {
    const int*   batch_user = (const int*)d_in[0];
    const int*   batch_pos  = (const int*)d_in[1];
    const int*   batch_neg  = (const int*)d_in[2];
    const float* U     = (const float*)d_in[3];
    const float* V     = (const float*)d_in[4];
    const float* W0    = (const float*)d_in[5];
    const float* b0    = (const float*)d_in[6];
    const float* W1    = (const float*)d_in[7];
    const float* b1    = (const float*)d_in[8];
    const int*   S_row = (const int*)d_in[9];
    const int*   S_col = (const int*)d_in[10];
    const float* S_val = (const float*)d_in[11];
    const int*   R_row = (const int*)d_in[12];
    const int*   R_col = (const int*)d_in[13];
    const float* R_val = (const float*)d_in[14];
    float* out = (float*)d_out;

    const size_t tabElems = (size_t)NUM_USERS * EMBED;   // 6.4M floats

    // workspace layout (byte offsets). tmpRow aliases A, tmpCV aliases B:
    // both are dead before A/B are first written by layer0/SpMM1.
    char* wsb = (char*)d_ws;
    size_t o = 0;
    float* A       = (float*)(wsb + o); o += tabElems * 4;            // U1 (alias: tmpRow)
    float* B       = (float*)(wsb + o); o += tabElems * 4;            // agg (alias: tmpCV)
    float* Agg2    = (float*)(wsb + o); o += (size_t)BATCH * EMBED * 4;
    int*   rowptrS = (int*)(wsb + o);   o += (NUM_USERS + 1) * 4;
    int*   cnt_t   = (int*)(wsb + o);   o += (size_t)NB * NCH * 4;    // 256 KB
    int*   bsums   = (int*)(wsb + o);   o += 1024 * 4;
    int*   head    = (int*)(wsb + o);   o += NUM_USERS * 4;
    int*   nxt     = (int*)(wsb + o);   o += BATCH * 4;
    o = (o + 7) & ~(size_t)7;
    int2*  colvalS = (int2*)(wsb + o);  o += (size_t)S_NNZ * 8;

    int*  tmpRow = (int*)A;
    int2* tmpCV  = (int2*)B;

    const int spmm_blocks  = (NUM_USERS * 64 + 255) / 256;
    const int layer_blocks = (NUM_USERS + 15) / 16;

    // ---- CSR of S: two-pass bucket sort ----
    k_p1hist<<<NCH, 256, 0, stream>>>(S_row, cnt_t);
    k_scan1<<<(NB * NCH) / 1024, 1024, 0, stream>>>(cnt_t, cnt_t, bsums, NB * NCH);
    k_scan2<<<1, 1024, 0, stream>>>(bsums, (NB * NCH) / 1024, &bsums[512]);
    k_scan3b<<<(NB * NCH) / 256, 256, 0, stream>>>(cnt_t, bsums, NB * NCH);
    k_p1scatter<<<NCH, 256, 0, stream>>>(S_row, S_col, S_val, cnt_t, tmpRow, tmpCV);
    k_p2<<<NB, 512, 0, stream>>>(tmpRow, tmpCV, cnt_t, rowptrS, colvalS);

    // ---- layer 0 (full) ----
    k_spmm_csr<<<spmm_blocks, 256, 0, stream>>>(rowptrS, colvalS, U, B, NUM_USERS);
    k_layer<<<layer_blocks, 256, 0, stream>>>(B, U, A, W0, b0);

    // ---- chain map for R (user -> batch slots) ----
    hipMemsetAsync(head, 0xFF, NUM_USERS * sizeof(int), stream);
    k_chain<<<(BATCH + 255) / 256, 256, 0, stream>>>(batch_user, head, nxt, BATCH);

    // ---- layer 1 (batch-restricted), writes u2 into out0 ----
    k_spmm_batch<<<(BATCH * 64 + 255) / 256, 256, 0, stream>>>(rowptrS, colvalS, A, batch_user, Agg2, BATCH);
    k_layer_batch<<<(BATCH + 15) / 16, 256, 0, stream>>>(Agg2, A, batch_user, out, W1, b1);

    // ---- out0 += (R @ V)[batch rows] ----
    k_filter<<<(R_NNZ + 255) / 256, 256, 0, stream>>>(R_row, R_col, R_val, head, nxt, V, out, R_NNZ);

    // ---- bp/bn gathers ----
    k_gather2<<<(BATCH * EMBED + 255) / 256, 256, 0, stream>>>(V, batch_pos, batch_neg, out);
}

// Round 10
// 599.292 us; speedup vs baseline: 1.4861x; 1.0382x over previous
//
#include <hip/hip_runtime.h>
#include <hip/hip_bf16.h>

#define NUM_USERS 100000
#define NUM_ITEMS 50000
#define EMBED     64
#define S_NNZ     (NUM_USERS * 32)
#define R_NNZ     (NUM_USERS * 50)
#define BATCH     8192

// bucket sort parameters: 256 buckets x 391 rows, 256 chunks x 12500 edges
#define NB    256
#define NCH   256
#define CHUNK (S_NNZ / NCH)      // 12500
#define BROWS 391                // 391*256 = 100096 >= NUM_USERS

// ---------------- two-pass bucket CSR build ----------------

// pass 1a: per-chunk bucket histogram -> cnt_t[bucket*NCH + chunk]
__global__ __launch_bounds__(256) void k_p1hist(const int* __restrict__ rows, int* __restrict__ cnt_t) {
    __shared__ int h[NB];
    int t = threadIdx.x, b = blockIdx.x;
    h[t] = 0;
    __syncthreads();
    int base = b * CHUNK;
    for (int i = t; i < CHUNK; i += 256) atomicAdd(&h[rows[base + i] / BROWS], 1);
    __syncthreads();
    cnt_t[t * NCH + b] = h[t];
}

// flat exclusive scan over 65536 ints
__global__ __launch_bounds__(1024) void k_scan1(const int* __restrict__ cnt, int* __restrict__ excl,
                                                int* __restrict__ bsums, int n) {
    __shared__ int buf[1024];
    int t = threadIdx.x;
    int i = blockIdx.x * 1024 + t;
    int x = (i < n) ? cnt[i] : 0;
    buf[t] = x;
    __syncthreads();
    for (int off = 1; off < 1024; off <<= 1) {
        int y = (t >= off) ? buf[t - off] : 0;
        __syncthreads();
        buf[t] += y;
        __syncthreads();
    }
    if (i < n) excl[i] = buf[t] - x;
    if (t == 1023) bsums[blockIdx.x] = buf[1023];
}

__global__ __launch_bounds__(1024) void k_scan2(int* __restrict__ bsums, int nb, int* __restrict__ total_slot) {
    __shared__ int buf[1024];
    int t = threadIdx.x;
    int x = (t < nb) ? bsums[t] : 0;
    buf[t] = x;
    __syncthreads();
    for (int off = 1; off < 1024; off <<= 1) {
        int y = (t >= off) ? buf[t - off] : 0;
        __syncthreads();
        buf[t] += y;
        __syncthreads();
    }
    if (t < nb) bsums[t] = buf[t] - x;
    if (t == 1023) total_slot[0] = buf[1023];
}

__global__ void k_scan3b(int* __restrict__ a, const int* __restrict__ bsums, int n) {
    int i = blockIdx.x * blockDim.x + threadIdx.x;
    if (i < n) a[i] += bsums[i >> 10];
}

// pass 1b: write chunk's edges into per-(chunk,bucket) contiguous runs.
// packed: x = (rowloc<<17)|col (rowloc<391 fits 9b, col<2^17), y = val bits
__global__ __launch_bounds__(256) void k_p1scatter(const int* __restrict__ rows, const int* __restrict__ cols,
                                                   const float* __restrict__ vals, const int* __restrict__ cnt_t,
                                                   int2* __restrict__ tmpE) {
    __shared__ int cur[NB];
    int t = threadIdx.x, b = blockIdx.x;
    cur[t] = cnt_t[t * NCH + b];
    __syncthreads();
    int base = b * CHUNK;
    for (int i = t; i < CHUNK; i += 256) {
        int e  = base + i;
        int r  = rows[e];
        int bk = r / BROWS;
        int pos = atomicAdd(&cur[bk], 1);
        tmpE[pos] = make_int2(((r - bk * BROWS) << 17) | cols[e], __float_as_int(vals[e]));
    }
}

// pass 2: exact CSR within each bucket (100 KB window, one block) + rowptr
__global__ __launch_bounds__(512) void k_p2(const int2* __restrict__ tmpE, const int* __restrict__ cnt_t,
                                            int* __restrict__ rowptr, int2* __restrict__ colval) {
    __shared__ int h[512];
    __shared__ int s[512];
    __shared__ int cur[512];
    int t = threadIdx.x, k = blockIdx.x;
    int beg = cnt_t[k * NCH];
    int end = (k < NB - 1) ? cnt_t[(k + 1) * NCH] : S_NNZ;
    h[t] = 0;
    __syncthreads();
    for (int j = beg + t; j < end; j += 512) atomicAdd(&h[((unsigned)tmpE[j].x) >> 17], 1);
    __syncthreads();
    s[t] = h[t];
    __syncthreads();
    for (int off = 1; off < 512; off <<= 1) {
        int y = (t >= off) ? s[t - off] : 0;
        __syncthreads();
        s[t] += y;
        __syncthreads();
    }
    int excl = s[t] - h[t];
    int gr   = k * BROWS + t;
    if (t <= BROWS && gr <= NUM_USERS) rowptr[gr] = beg + excl;
    cur[t] = beg + excl;
    __syncthreads();
    for (int j = beg + t; j < end; j += 512) {
        int2 e  = tmpE[j];
        int pos = atomicAdd(&cur[((unsigned)e.x) >> 17], 1);
        colval[pos] = make_int2(e.x & 0x1FFFF, e.y);
    }
}

// ---------------- converts ----------------
__global__ void k_cvt(const float* __restrict__ src, __hip_bfloat16* __restrict__ dst, int n) {
    int i = blockIdx.x * blockDim.x + threadIdx.x;
    if (i < n) dst[i] = __float2bfloat16(src[i]);
}

// ---------------- SpMM (CSR gather, bf16 table, unroll x8) ----------------
__global__ __launch_bounds__(256) void k_spmm16(const int* __restrict__ rowptr,
                                                const int2* __restrict__ colval,
                                                const __hip_bfloat16* __restrict__ X,
                                                float* __restrict__ Y, int n_rows) {
    int w    = blockIdx.x * (blockDim.x >> 6) + (threadIdx.x >> 6);
    int lane = threadIdx.x & 63;
    if (w >= n_rows) return;
    int beg = rowptr[w], end = rowptr[w + 1];
    float acc = 0.0f;
    int j    = beg;
    int jend = beg + ((end - beg) & ~7);
    for (; j < jend; j += 8) {
        int2 cv[8];
#pragma unroll
        for (int u = 0; u < 8; ++u) cv[u] = colval[j + u];
        float x[8];
#pragma unroll
        for (int u = 0; u < 8; ++u) x[u] = __bfloat162float(X[(size_t)cv[u].x * EMBED + lane]);
#pragma unroll
        for (int u = 0; u < 8; ++u) acc = fmaf(__int_as_float(cv[u].y), x[u], acc);
    }
    for (; j < end; ++j)
        acc = fmaf(__int_as_float(colval[j].y), __bfloat162float(X[(size_t)colval[j].x * EMBED + lane]), acc);
    Y[(size_t)w * EMBED + lane] = acc;
}

__global__ __launch_bounds__(256) void k_spmm_batch16(const int* __restrict__ rowptr,
                                                      const int2* __restrict__ colval,
                                                      const __hip_bfloat16* __restrict__ X,
                                                      const int* __restrict__ bu,
                                                      float* __restrict__ Agg2, int n) {
    int w    = blockIdx.x * (blockDim.x >> 6) + (threadIdx.x >> 6);
    int lane = threadIdx.x & 63;
    if (w >= n) return;
    int r   = bu[w];
    int beg = rowptr[r], end = rowptr[r + 1];
    float acc = 0.0f;
    int j    = beg;
    int jend = beg + ((end - beg) & ~7);
    for (; j < jend; j += 8) {
        int2 cv[8];
#pragma unroll
        for (int u = 0; u < 8; ++u) cv[u] = colval[j + u];
        float x[8];
#pragma unroll
        for (int u = 0; u < 8; ++u) x[u] = __bfloat162float(X[(size_t)cv[u].x * EMBED + lane]);
#pragma unroll
        for (int u = 0; u < 8; ++u) acc = fmaf(__int_as_float(cv[u].y), x[u], acc);
    }
    for (; j < end; ++j)
        acc = fmaf(__int_as_float(colval[j].y), __bfloat162float(X[(size_t)colval[j].x * EMBED + lane]), acc);
    Agg2[(size_t)w * EMBED + lane] = acc;
}

// ---------------- dense layers ----------------
// layer0: writes fp32 Uout AND bf16 Uout16 (gather table for SpMM2)
__global__ __launch_bounds__(256) void k_layer(const float* __restrict__ Agg,
                                               const float* __restrict__ Uin,
                                               float* __restrict__ Uout,
                                               __hip_bfloat16* __restrict__ Uout16,
                                               const float* __restrict__ W,
                                               const float* __restrict__ b) {
    __shared__ float Wl[128 * 64];
    __shared__ float xs[16][128];
    int t = threadIdx.x;
    for (int i = t; i < 128 * 64; i += 256) Wl[i] = W[i];
    int rl = t >> 6;
    int c  = t & 63;
    int rbase = blockIdx.x * 16;
#pragma unroll
    for (int q = 0; q < 4; ++q) {
        int rr = rbase + rl * 4 + q;
        if (rr < NUM_USERS) {
            xs[rl * 4 + q][c]      = Agg[(size_t)rr * EMBED + c];
            xs[rl * 4 + q][64 + c] = Uin[(size_t)rr * EMBED + c];
        }
    }
    __syncthreads();
    float bias = b[c];
#pragma unroll
    for (int q = 0; q < 4; ++q) {
        int rr = rbase + rl * 4 + q;
        if (rr >= NUM_USERS) break;
        float acc = bias;
#pragma unroll
        for (int k = 0; k < 128; ++k) acc = fmaf(xs[rl * 4 + q][k], Wl[k * 64 + c], acc);
        float v = fmaxf(acc, 0.0f);
        Uout[(size_t)rr * EMBED + c]   = v;
        Uout16[(size_t)rr * EMBED + c] = __float2bfloat16(v);
    }
}

__global__ __launch_bounds__(256) void k_layer_batch(const float* __restrict__ Agg2,
                                                     const float* __restrict__ Uin,
                                                     const int* __restrict__ bu,
                                                     float* __restrict__ out0,
                                                     const float* __restrict__ W,
                                                     const float* __restrict__ b) {
    __shared__ float Wl[128 * 64];
    __shared__ float xs[16][128];
    int t = threadIdx.x;
    for (int i = t; i < 128 * 64; i += 256) Wl[i] = W[i];
    int rl = t >> 6;
    int c  = t & 63;
    int rbase = blockIdx.x * 16;
#pragma unroll
    for (int q = 0; q < 4; ++q) {
        int s = rbase + rl * 4 + q;
        if (s < BATCH) {
            xs[rl * 4 + q][c]      = Agg2[(size_t)s * EMBED + c];
            xs[rl * 4 + q][64 + c] = Uin[(size_t)bu[s] * EMBED + c];
        }
    }
    __syncthreads();
    float bias = b[c];
#pragma unroll
    for (int q = 0; q < 4; ++q) {
        int s = rbase + rl * 4 + q;
        if (s >= BATCH) break;
        float acc = bias;
#pragma unroll
        for (int k = 0; k < 128; ++k) acc = fmaf(xs[rl * 4 + q][k], Wl[k * 64 + c], acc);
        out0[(size_t)s * EMBED + c] = fmaxf(acc, 0.0f);
    }
}

// ---------------- R handling (no CSR): chain map + edge filter ----------------

__global__ void k_chain(const int* __restrict__ bu, int* __restrict__ head,
                        int* __restrict__ nxt, int n) {
    int i = blockIdx.x * blockDim.x + threadIdx.x;
    if (i < n) nxt[i] = atomicExch(&head[bu[i]], i);
}

__global__ __launch_bounds__(256) void k_filter16(const int* __restrict__ rows,
                                                  const int* __restrict__ cols,
                                                  const float* __restrict__ vals,
                                                  const int* __restrict__ head,
                                                  const int* __restrict__ nxt,
                                                  const __hip_bfloat16* __restrict__ V16,
                                                  float* __restrict__ out0, int nnz) {
    int e    = blockIdx.x * blockDim.x + threadIdx.x;
    int lane = threadIdx.x & 63;
    int r = (e < nnz) ? rows[e] : -1;
    int h = (r >= 0) ? head[r] : -1;
    unsigned long long mask = __ballot(h >= 0);
    int   c = 0;
    float v = 0.0f;
    if (h >= 0) { c = cols[e]; v = vals[e]; }
    while (mask) {
        int l = __ffsll((long long)mask) - 1;
        mask &= mask - 1;
        int   cc = __shfl(c, l);
        float vv = __shfl(v, l);
        int   hh = __shfl(h, l);
        float x  = vv * __bfloat162float(V16[(size_t)cc * EMBED + lane]);
        while (hh >= 0) {
            atomicAdd(&out0[(size_t)hh * EMBED + lane], x);
            hh = nxt[hh];
        }
    }
}

// ---------------- final gathers (bp/bn only, exact fp32 V) ----------------
__global__ void k_gather2(const float* __restrict__ V,
                          const int* __restrict__ bp, const int* __restrict__ bn,
                          float* __restrict__ out) {
    int i = blockIdx.x * blockDim.x + threadIdx.x;
    if (i >= BATCH * EMBED) return;
    int row = i >> 6, l = i & 63;
    out[BATCH * EMBED + i]     = V[(size_t)bp[row] * EMBED + l];
    out[2 * BATCH * EMBED + i] = V[(size_t)bn[row] * EMBED + l];
}

// ---------------- launch ----------------

extern "C" void kernel_launch(void* const* d_in, const int* in_sizes, int n_in,
                              void* d_out, int out_size, void* d_ws, size_t ws_size,
                              hipStream_t stream) {
    const int*   batch_user = (const int*)d_in[0];
    const int*   batch_pos  = (const int*)d_in[1];
    const int*   batch_neg  = (const int*)d_in[2];
    const float* U     = (const float*)d_in[3];
    const float* V     = (const float*)d_in[4];
    const float* W0    = (const float*)d_in[5];
    const float* b0    = (const float*)d_in[6];
    const float* W1    = (const float*)d_in[7];
    const float* b1    = (const float*)d_in[8];
    const int*   S_row = (const int*)d_in[9];
    const int*   S_col = (const int*)d_in[10];
    const float* S_val = (const float*)d_in[11];
    const int*   R_row = (const int*)d_in[12];
    const int*   R_col = (const int*)d_in[13];
    const float* R_val = (const float*)d_in[14];
    float* out = (float*)d_out;

    const size_t tabElems = (size_t)NUM_USERS * EMBED;   // 6.4M

    // workspace layout. tmpE aliases A (both 25.6 MB; tmpE dead before A written).
    // X16 region (12.8 MB) sequentially holds U16 -> A16 -> V16.
    char* wsb = (char*)d_ws;
    size_t o = 0;
    float* A       = (float*)(wsb + o); o += tabElems * 4;            // U1 fp32 (alias: tmpE)
    float* B       = (float*)(wsb + o); o += tabElems * 4;            // agg fp32
    float* Agg2    = (float*)(wsb + o); o += (size_t)BATCH * EMBED * 4;
    int*   rowptrS = (int*)(wsb + o);   o += (NUM_USERS + 1) * 4;
    int*   cnt_t   = (int*)(wsb + o);   o += (size_t)NB * NCH * 4;
    int*   bsums   = (int*)(wsb + o);   o += 1024 * 4;
    int*   head    = (int*)(wsb + o);   o += NUM_USERS * 4;
    int*   nxt     = (int*)(wsb + o);   o += BATCH * 4;
    o = (o + 7) & ~(size_t)7;
    int2*  colvalS = (int2*)(wsb + o);  o += (size_t)S_NNZ * 8;
    __hip_bfloat16* X16 = (__hip_bfloat16*)(wsb + o); o += tabElems * 2;

    int2* tmpE = (int2*)A;

    const int spmm_blocks  = (NUM_USERS * 64 + 255) / 256;
    const int layer_blocks = (NUM_USERS + 15) / 16;

    // ---- CSR of S: two-pass bucket sort ----
    k_p1hist<<<NCH, 256, 0, stream>>>(S_row, cnt_t);
    k_scan1<<<(NB * NCH) / 1024, 1024, 0, stream>>>(cnt_t, cnt_t, bsums, NB * NCH);
    k_scan2<<<1, 1024, 0, stream>>>(bsums, (NB * NCH) / 1024, &bsums[512]);
    k_scan3b<<<(NB * NCH) / 256, 256, 0, stream>>>(cnt_t, bsums, NB * NCH);
    k_p1scatter<<<NCH, 256, 0, stream>>>(S_row, S_col, S_val, cnt_t, tmpE);
    k_p2<<<NB, 512, 0, stream>>>(tmpE, cnt_t, rowptrS, colvalS);

    // ---- layer 0 (full): U16 table, SpMM1, layer (emits A + A16) ----
    k_cvt<<<(int)((tabElems + 255) / 256), 256, 0, stream>>>(U, X16, (int)tabElems);
    k_spmm16<<<spmm_blocks, 256, 0, stream>>>(rowptrS, colvalS, X16, B, NUM_USERS);
    k_layer<<<layer_blocks, 256, 0, stream>>>(B, U, A, X16, W0, b0);   // X16 now = A16

    // ---- chain map for R (user -> batch slots) ----
    hipMemsetAsync(head, 0xFF, NUM_USERS * sizeof(int), stream);
    k_chain<<<(BATCH + 255) / 256, 256, 0, stream>>>(batch_user, head, nxt, BATCH);

    // ---- layer 1 (batch-restricted), writes u2 into out0 ----
    k_spmm_batch16<<<(BATCH * 64 + 255) / 256, 256, 0, stream>>>(rowptrS, colvalS, X16, batch_user, Agg2, BATCH);
    k_layer_batch<<<(BATCH + 15) / 16, 256, 0, stream>>>(Agg2, A, batch_user, out, W1, b1);

    // ---- out0 += (R @ V)[batch rows], V as bf16 table ----
    k_cvt<<<(int)(((size_t)NUM_ITEMS * EMBED + 255) / 256), 256, 0, stream>>>(V, X16, NUM_ITEMS * EMBED); // X16 now = V16
    k_filter16<<<(R_NNZ + 255) / 256, 256, 0, stream>>>(R_row, R_col, R_val, head, nxt, X16, out, R_NNZ);

    // ---- bp/bn gathers (exact fp32 V) ----
    k_gather2<<<(BATCH * EMBED + 255) / 256, 256, 0, stream>>>(V, batch_pos, batch_neg, out);
}